// Round 13
// baseline (214.303 us; speedup 1.0000x reference)
//
#include <hip/hip_runtime.h>
#include <hip/hip_cooperative_groups.h>

namespace cg = cooperative_groups;

#define IN_C 64
#define OUT_C 64

typedef __attribute__((ext_vector_type(8))) short bf16x8;
typedef __attribute__((ext_vector_type(4))) float f32x4;

// fp32 -> bf16 (RNE), bit-level, finite inputs
__device__ __forceinline__ short f2bf(float f) {
    unsigned u = __float_as_uint(f);
    unsigned r = (u + 0x7FFFu + ((u >> 16) & 1u)) >> 16;
    return (short)r;
}

#define UNPACK_ADD(v)                                   \
    do {                                                \
        acc[0] += __uint_as_float((v).x << 16);         \
        acc[1] += __uint_as_float((v).x & 0xFFFF0000u); \
        acc[2] += __uint_as_float((v).y << 16);         \
        acc[3] += __uint_as_float((v).y & 0xFFFF0000u); \
        acc[4] += __uint_as_float((v).z << 16);         \
        acc[5] += __uint_as_float((v).z & 0xFFFF0000u); \
        acc[6] += __uint_as_float((v).w << 16);         \
        acc[7] += __uint_as_float((v).w & 0xFFFF0000u); \
    } while (0)

// ---------------- device bodies (shared by fused + fallback) ------------

// One 16-node MFMA tile (wave-level). wlds holds fragment-ready bf16 W,
// bfr the 8 B-fragments already in registers.
__device__ __forceinline__ void gemm_tile_body(
    const float* __restrict__ x, unsigned short* __restrict__ h,
    int n_nodes, int tile, const bf16x8 bfr[2][4], int m, int g) {
    const int node0 = tile * 16;
    if (node0 >= n_nodes) return;

    const int arow = min(node0 + m, n_nodes - 1);
    const float* xr = x + (size_t)arow * IN_C;
    bf16x8 afr[2];
    #pragma unroll
    for (int ks = 0; ks < 2; ++ks) {
        const float4 p0 = *(const float4*)(xr + ks * 32 + g * 8);
        const float4 p1 = *(const float4*)(xr + ks * 32 + g * 8 + 4);
        union { short s[8]; bf16x8 v; } u;
        u.s[0] = f2bf(p0.x); u.s[1] = f2bf(p0.y);
        u.s[2] = f2bf(p0.z); u.s[3] = f2bf(p0.w);
        u.s[4] = f2bf(p1.x); u.s[5] = f2bf(p1.y);
        u.s[6] = f2bf(p1.z); u.s[7] = f2bf(p1.w);
        afr[ks] = u.v;
    }

    f32x4 acc[4];
    #pragma unroll
    for (int nt = 0; nt < 4; ++nt) acc[nt] = (f32x4){0.f, 0.f, 0.f, 0.f};
    #pragma unroll
    for (int ks = 0; ks < 2; ++ks) {
        #pragma unroll
        for (int nt = 0; nt < 4; ++nt) {
            acc[nt] = __builtin_amdgcn_mfma_f32_16x16x32_bf16(
                afr[ks], bfr[ks][nt], acc[nt], 0, 0, 0);
        }
    }

    // C layout (m89-verified): col=lane&15 (=m), row=(lane>>4)*4+reg (=g*4+j)
    #pragma unroll
    for (int j = 0; j < 4; ++j) {
        const int node = node0 + g * 4 + j;
        if (node < n_nodes) {
            #pragma unroll
            for (int nt = 0; nt < 4; ++nt) {
                h[(size_t)node * OUT_C + nt * 16 + m] =
                    (unsigned short)f2bf(acc[nt][j]);
            }
        }
    }
}

// Cooperative W stage into fragment-ready bf16 LDS layout.
__device__ __forceinline__ void stage_w_body(
    const float* __restrict__ w, bf16x8* wlds, int tid) {
    #pragma unroll
    for (int i = tid; i < IN_C * OUT_C; i += 256) {
        const int k = i >> 6, c = i & 63;
        const int ks = k >> 5, gg = (k >> 3) & 3, j = k & 7;
        const int nt = c >> 4, mm = c & 15;
        ((short*)wlds)[((ks * 4 + nt) * 64 + gg * 16 + mm) * 8 + j] =
            f2bf(w[i]);
    }
}

// rowptr fill: work-item t covers edges [t*4, t*4+4).
__device__ __forceinline__ void rowptr_body(
    const int* __restrict__ row, int* __restrict__ rowptr,
    int n_nodes, int n_edges, int t) {
    const int e0 = t * 4;
    if (e0 >= n_edges) return;
    const int4 r4 = *(const int4*)(row + e0);
    int rprev = (e0 == 0) ? -1 : row[e0 - 1];
    int rr[4] = {r4.x, r4.y, r4.z, r4.w};
    #pragma unroll
    for (int i = 0; i < 4; ++i) {
        if (e0 + i < n_edges) {
            for (int n = rprev + 1; n <= rr[i]; ++n) rowptr[n] = e0 + i;
            rprev = rr[i];
        }
    }
    if (e0 + 4 >= n_edges) {
        for (int n = rprev + 1; n <= n_nodes; ++n) rowptr[n] = n_edges;
    }
}

// agg for one node, 8-lane group (lo = channel octet). Unroll-8.
__device__ __forceinline__ void agg_body(
    const uint4* __restrict__ h4, const int* __restrict__ col,
    const int* __restrict__ rowptr, const float* __restrict__ deg,
    const float4* __restrict__ bias4, float4* __restrict__ out4,
    int node, int lo) {
    const int begin = rowptr[node];
    const int end   = rowptr[node + 1];
    const int last  = end - 1;

    float acc[8] = {0.f, 0.f, 0.f, 0.f, 0.f, 0.f, 0.f, 0.f};
    for (int e = begin; e < end; e += 8) {
        int c[8];
        #pragma unroll
        for (int i = 0; i < 8; ++i) c[i] = col[min(e + i, last)];
        uint4 v[8];
        #pragma unroll
        for (int i = 0; i < 8; ++i) v[i] = h4[(size_t)c[i] * 8 + lo];
        UNPACK_ADD(v[0]);
        #pragma unroll
        for (int i = 1; i < 8; ++i) {
            if (e + i <= last) UNPACK_ADD(v[i]);
        }
    }

    const float  d  = deg[node];
    const float4 b0 = bias4[lo * 2];
    const float4 b1 = bias4[lo * 2 + 1];
    float4 oa, ob;
    oa.x = fmaf(acc[0], d, b0.x);
    oa.y = fmaf(acc[1], d, b0.y);
    oa.z = fmaf(acc[2], d, b0.z);
    oa.w = fmaf(acc[3], d, b0.w);
    ob.x = fmaf(acc[4], d, b1.x);
    ob.y = fmaf(acc[5], d, b1.y);
    ob.z = fmaf(acc[6], d, b1.z);
    ob.w = fmaf(acc[7], d, b1.w);
    out4[(size_t)node * 16 + lo * 2]     = oa;
    out4[(size_t)node * 16 + lo * 2 + 1] = ob;
}

// ---------------- fused cooperative kernel ------------------------------
// Phase 1 (grid-stride): GEMM tiles + rowptr build. W staged + B-frags
// loaded ONCE per block (identical across items). grid.sync(). Phase 2
// (grid-stride): agg. No early returns before the sync.
__global__ __launch_bounds__(256, 4) void gcn_fused_kernel(
    const float* __restrict__ x, const float* __restrict__ w,
    const int* __restrict__ row, const int* __restrict__ col,
    const float* __restrict__ deg, const float4* __restrict__ bias4,
    unsigned short* __restrict__ h, int* __restrict__ rowptr,
    float4* __restrict__ out4,
    int n_nodes, int n_edges,
    int gemm_blocks, int rowptr_blocks, int agg_blocks, int nblocks) {
    __shared__ bf16x8 wlds[512];   // 8 KB fragment-ready W
    const int tid  = threadIdx.x;
    const int lane = tid & 63;
    const int wv   = tid >> 6;
    const int m    = lane & 15;
    const int g    = lane >> 4;

    stage_w_body(w, wlds, tid);
    __syncthreads();

    bf16x8 bfr[2][4];
    #pragma unroll
    for (int ks = 0; ks < 2; ++ks) {
        #pragma unroll
        for (int nt = 0; nt < 4; ++nt) {
            bfr[ks][nt] = wlds[(ks * 4 + nt) * 64 + g * 16 + m];
        }
    }

    const int p1 = gemm_blocks + rowptr_blocks;
    for (int b = blockIdx.x; b < p1; b += nblocks) {
        if (b < gemm_blocks) {
            gemm_tile_body(x, h, n_nodes, b * 4 + wv, bfr, m, g);
        } else {
            rowptr_body(row, rowptr, n_nodes, n_edges,
                        (b - gemm_blocks) * 256 + tid);
        }
    }

    cg::this_grid().sync();

    const uint4* h4 = (const uint4*)h;
    const int lo = tid & 7;
    for (int b = blockIdx.x; b < agg_blocks; b += nblocks) {
        const int node = b * 32 + (tid >> 3);
        if (node < n_nodes) {
            agg_body(h4, col, rowptr, deg, bias4, out4, node, lo);
        }
    }
}

// ---------------- fallback two-kernel path ------------------------------
__global__ __launch_bounds__(256) void gcn_prep_kernel(
    const float* __restrict__ x, const float* __restrict__ w,
    unsigned short* __restrict__ h,
    const int* __restrict__ row, int* __restrict__ rowptr,
    int n_nodes, int n_edges, int gemm_blocks) {
    if ((int)blockIdx.x < gemm_blocks) {
        __shared__ bf16x8 wlds[512];
        const int tid  = threadIdx.x;
        const int lane = tid & 63;
        const int wv   = tid >> 6;
        const int m    = lane & 15;
        const int g    = lane >> 4;
        stage_w_body(w, wlds, tid);
        __syncthreads();
        bf16x8 bfr[2][4];
        #pragma unroll
        for (int ks = 0; ks < 2; ++ks) {
            #pragma unroll
            for (int nt = 0; nt < 4; ++nt) {
                bfr[ks][nt] = wlds[(ks * 4 + nt) * 64 + g * 16 + m];
            }
        }
        gemm_tile_body(x, h, n_nodes, (int)blockIdx.x * 4 + wv, bfr, m, g);
    } else {
        rowptr_body(row, rowptr, n_nodes, n_edges,
                    ((int)blockIdx.x - gemm_blocks) * 256 + threadIdx.x);
    }
}

__global__ __launch_bounds__(256) void gcn_agg_kernel(
    const uint4* __restrict__ h4, const int* __restrict__ col,
    const int* __restrict__ rowptr, const float* __restrict__ deg,
    const float4* __restrict__ bias4, float4* __restrict__ out4,
    int n_nodes) {
    const int node = blockIdx.x * 32 + (threadIdx.x >> 3);
    if (node >= n_nodes) return;
    agg_body(h4, col, rowptr, deg, bias4, out4, node, threadIdx.x & 7);
}

extern "C" void kernel_launch(void* const* d_in, const int* in_sizes, int n_in,
                              void* d_out, int out_size, void* d_ws, size_t ws_size,
                              hipStream_t stream) {
    const float* x    = (const float*)d_in[0];
    const float* w    = (const float*)d_in[1];
    const float4* bias4 = (const float4*)d_in[2];
    const int* col    = (const int*)d_in[3];
    const int* row    = (const int*)d_in[4];
    const float* deg  = (const float*)d_in[5];
    float4* out4      = (float4*)d_out;

    const int n_nodes = in_sizes[5];
    const int n_edges = in_sizes[3];

    unsigned short* h = (unsigned short*)d_ws;            // N*64 bf16 = 12.8 MB
    int* rowptr = (int*)((char*)d_ws +
                         (size_t)n_nodes * OUT_C * sizeof(unsigned short));

    int gemm_blocks   = (n_nodes + 63) / 64;
    int rowptr_blocks = (n_edges + 1023) / 1024;
    int agg_blocks    = (n_nodes + 31) / 32;

    // cooperative fused path
    int maxb = 0;
    hipError_t qerr = hipOccupancyMaxActiveBlocksPerMultiprocessor(
        &maxb, gcn_fused_kernel, 256, 0);
    if (qerr == hipSuccess && maxb > 0) {
        int nblocks = maxb * 256;                 // 256 CUs on MI355X
        if (nblocks > 2048) nblocks = 2048;
        void* args[] = {
            (void*)&x, (void*)&w, (void*)&row, (void*)&col, (void*)&deg,
            (void*)&bias4, (void*)&h, (void*)&rowptr, (void*)&out4,
            (void*)&n_nodes, (void*)&n_edges,
            (void*)&gemm_blocks, (void*)&rowptr_blocks, (void*)&agg_blocks,
            (void*)&nblocks};
        hipError_t lerr = hipLaunchCooperativeKernel(
            gcn_fused_kernel, dim3(nblocks), dim3(256), args, 0u, stream);
        if (lerr == hipSuccess) return;
    }

    // fallback: proven two-kernel path
    gcn_prep_kernel<<<gemm_blocks + rowptr_blocks, 256, 0, stream>>>(
        x, w, h, row, rowptr, n_nodes, n_edges, gemm_blocks);
    gcn_agg_kernel<<<agg_blocks, 256, 0, stream>>>(
        (const uint4*)h, col, rowptr, deg, bias4, out4, n_nodes);
}